// Round 4
// baseline (110.594 us; speedup 1.0000x reference)
//
#include <hip/hip_runtime.h>
#include <hip/hip_bf16.h>

typedef __attribute__((ext_vector_type(8))) short bf16x8;
typedef __attribute__((ext_vector_type(4))) float f32x4;

#define B_ 8
#define S_ 1024
#define R_ 16384
#define H_ 128
#define D_ 256     // input dim = 2H
#define F_ 384     // inter dim

__device__ __forceinline__ unsigned short f2bf(float x) {
    unsigned int u = __float_as_uint(x);
    u += 0x7FFF + ((u >> 16) & 1);   // round-to-nearest-even
    return (unsigned short)(u >> 16);
}

__device__ __forceinline__ unsigned pack2bf(float a, float b) {
    float2 t; t.x = a; t.y = b;
    __hip_bfloat162 h = __float22bfloat162_rn(t);   // v_cvt_pk_bf16_f32
    return *reinterpret_cast<unsigned*>(&h);
}

// One fused prep kernel: span fp32->bf16, W1 transpose+cvt, W2 transpose+cvt.
// grid = 1024 (span, float4/thread) + 384 (W1T) + 192 (W2T) = 1600 blocks.
__global__ __launch_bounds__(256) void k_prep(const float* __restrict__ span,
                                              const float* __restrict__ W1,
                                              const float* __restrict__ W2,
                                              unsigned short* __restrict__ spanbf,
                                              unsigned short* __restrict__ W1T,
                                              unsigned short* __restrict__ W2T) {
    const int bid = blockIdx.x;
    const int t = threadIdx.x;
    if (bid < 1024) {
        int i = bid * 256 + t;
        float4 v = reinterpret_cast<const float4*>(span)[i];
        ushort4 o;
        o.x = f2bf(v.x); o.y = f2bf(v.y); o.z = f2bf(v.z); o.w = f2bf(v.w);
        reinterpret_cast<ushort4*>(spanbf)[i] = o;
    } else if (bid < 1408) {
        int i = (bid - 1024) * 256 + t;       // W1T[f][d] = W1[d][f]
        int d = i & 255, f = i >> 8;
        W1T[i] = f2bf(W1[d * F_ + f]);
    } else {
        int i = (bid - 1408) * 256 + t;       // W2T[o][f] = W2[f][o]
        int o = i / F_, f = i - o * F_;
        W2T[i] = f2bf(W2[f * H_ + o]);
    }
}

// 64 rows per block, 8 waves (512 threads). LDS 80 KiB, disjoint:
//   sA = [64][256] bf16 (32 KiB), row stride 512 B, XOR-swizzled  byte^=((m&7)<<4)
//   sH = [64][384] bf16 (48 KiB), row stride 768 B, same swizzle
// 2 barriers only: (stage -> L1 reads), (h writes -> L2 reads).
// Swizzle decomposition: read byte = m*stride + ((kt*64 + lg*16) ^ swz) with
// swz=(m&7)<<4 only collides with kt in bit 6 -> two base pointers per m-tile
// (kt even/odd), ds_read offsets are compile-time immediates (kt>>1)*128.
// Layer 1: wave w owns f in [w*48, w*48+48), all 64 rows (mt=0..3).
// Layer 2: wave (wr=w>>2, wc=w&3) owns rows [wr*32,+32) x o [wc*32,+32).
// Swapped mfma operands (W as A-operand): lane holds 4 consecutive f / o.
__global__ __launch_bounds__(512, 4) void k_main(
    const unsigned short* __restrict__ spanbf,
    const int* __restrict__ rel_ids,
    const unsigned short* __restrict__ W1T,
    const float* __restrict__ b1,
    const unsigned short* __restrict__ W2T,
    const float* __restrict__ b2,
    float* __restrict__ out)
{
    extern __shared__ char smem[];
    char* sA = smem;              // 32 KiB
    char* sH = smem + 32768;      // 48 KiB

    const int tid = threadIdx.x;
    const int blk = blockIdx.x;           // 0..2047
    const int m0  = blk << 6;             // 64 rows per block
    const int b   = m0 >> 14;
    const int r0  = m0 & 16383;

    const int w  = tid >> 6;   // wave 0..7
    const int l  = tid & 63;
    const int lr = l & 15;
    const int lg = l >> 4;

    // W1 row pointer for this lane; prefetch kt=0 fragments before the barrier
    const unsigned short* w1p = W1T + (unsigned)(w * 48 + lr) * 256 + lg * 8;
    bf16x8 Wpre0 = *reinterpret_cast<const bf16x8*>(w1p);
    bf16x8 Wpre1 = *reinterpret_cast<const bf16x8*>(w1p + 4096);
    bf16x8 Wpre2 = *reinterpret_cast<const bf16x8*>(w1p + 8192);

    // ---------------- stage A: gathered rel_reps (bf16) ----------------
    {
        const int m = tid >> 3;               // 0..63 local row
        const int e = tid & 7;                // eighth of the 512-B row
        const int2 ids = reinterpret_cast<const int2*>(rel_ids)[(b << 14) + r0 + m];
        const int idx = (e < 4) ? ids.x : ids.y;
        const uint4* src = reinterpret_cast<const uint4*>(
            spanbf + (((b << 10) + idx) << 7) + ((e & 3) << 5));
        const int base = m * 512 + e * 64;
        const int swz = (m & 7) << 4;
        #pragma unroll
        for (int j = 0; j < 4; ++j) {
            uint4 v = src[j];
            *reinterpret_cast<uint4*>(sA + ((base + j * 16) ^ swz)) = v;
        }
    }
    __syncthreads();                         // bar1: sA ready

    // ---------------- layer 1: h^T tiles = W1slice @ A^T ----------------
    // base pointers: even/odd kt per m-tile
    const char* aB[4][2];
    #pragma unroll
    for (int mt = 0; mt < 4; ++mt) {
        const int m = mt * 16 + lr;
        const int swz = (m & 7) << 4;
        const int e0 = m * 512 + ((lg << 4) ^ (swz & 0x30)) + (swz & 0x40);
        aB[mt][0] = sA + e0;
        aB[mt][1] = sA + (e0 ^ 64);
    }

    f32x4 acc[3][4];
    #pragma unroll
    for (int ft = 0; ft < 3; ++ft)
        #pragma unroll
        for (int mt = 0; mt < 4; ++mt) acc[ft][mt] = {0.f, 0.f, 0.f, 0.f};

    #pragma unroll
    for (int kt = 0; kt < 8; ++kt) {
        bf16x8 Af[4];
        #pragma unroll
        for (int mt = 0; mt < 4; ++mt)
            Af[mt] = *reinterpret_cast<const bf16x8*>(aB[mt][kt & 1] + (kt >> 1) * 128);
        #pragma unroll
        for (int ft = 0; ft < 3; ++ft) {
            bf16x8 Wf = (kt == 0) ? (ft == 0 ? Wpre0 : (ft == 1 ? Wpre1 : Wpre2))
                                  : *reinterpret_cast<const bf16x8*>(w1p + ft * 4096 + kt * 32);
            #pragma unroll
            for (int mt = 0; mt < 4; ++mt)
                acc[ft][mt] = __builtin_amdgcn_mfma_f32_16x16x32_bf16(
                    Wf, Af[mt], acc[ft][mt], 0, 0, 0);
        }
    }

    // ---------------- epilogue 1: bias + relu + packed b64 h store ----------
    #pragma unroll
    for (int ft = 0; ft < 3; ++ft) {
        const int fb = w * 48 + ft * 16 + lg * 4;      // first of 4 consecutive f
        const float4 bias = *reinterpret_cast<const float4*>(b1 + fb);
        #pragma unroll
        for (int mt = 0; mt < 4; ++mt) {
            float v0 = fmaxf(acc[ft][mt][0] + bias.x, 0.0f);
            float v1 = fmaxf(acc[ft][mt][1] + bias.y, 0.0f);
            float v2 = fmaxf(acc[ft][mt][2] + bias.z, 0.0f);
            float v3 = fmaxf(acc[ft][mt][3] + bias.w, 0.0f);
            uint2 p;
            p.x = pack2bf(v0, v1);
            p.y = pack2bf(v2, v3);
            const int m = mt * 16 + lr;
            *reinterpret_cast<uint2*>(
                sH + ((m * 768 + fb * 2) ^ ((m & 7) << 4))) = p;
        }
    }
    __syncthreads();                         // bar2: sH ready

    // ---------------- layer 2: out^T tiles = W2slice @ h^T (2D wave split) ----
    const int wr = w >> 2;     // row half   (32 rows)
    const int wc = w & 3;      // o group    (32 outputs)

    const char* hB[2][2];
    #pragma unroll
    for (int mt = 0; mt < 2; ++mt) {
        const int m = wr * 32 + mt * 16 + lr;
        const int swz = (m & 7) << 4;
        const int e0 = m * 768 + ((lg << 4) ^ (swz & 0x30)) + (swz & 0x40);
        hB[mt][0] = sH + e0;
        hB[mt][1] = sH + (e0 ^ 64);
    }
    const unsigned short* w2p = W2T + (unsigned)(wc * 32 + lr) * 384 + lg * 8;

    f32x4 acc2[2][2];
    #pragma unroll
    for (int nt = 0; nt < 2; ++nt)
        #pragma unroll
        for (int mt = 0; mt < 2; ++mt) acc2[nt][mt] = {0.f, 0.f, 0.f, 0.f};

    #pragma unroll
    for (int kt = 0; kt < 12; ++kt) {
        bf16x8 Hf0 = *reinterpret_cast<const bf16x8*>(hB[0][kt & 1] + (kt >> 1) * 128);
        bf16x8 Hf1 = *reinterpret_cast<const bf16x8*>(hB[1][kt & 1] + (kt >> 1) * 128);
        bf16x8 W20 = *reinterpret_cast<const bf16x8*>(w2p + kt * 32);
        bf16x8 W21 = *reinterpret_cast<const bf16x8*>(w2p + 6144 + kt * 32);
        acc2[0][0] = __builtin_amdgcn_mfma_f32_16x16x32_bf16(W20, Hf0, acc2[0][0], 0, 0, 0);
        acc2[0][1] = __builtin_amdgcn_mfma_f32_16x16x32_bf16(W20, Hf1, acc2[0][1], 0, 0, 0);
        acc2[1][0] = __builtin_amdgcn_mfma_f32_16x16x32_bf16(W21, Hf0, acc2[1][0], 0, 0, 0);
        acc2[1][1] = __builtin_amdgcn_mfma_f32_16x16x32_bf16(W21, Hf1, acc2[1][1], 0, 0, 0);
    }

    // ---------------- epilogue 2: bias + direct float4 global stores ----------
    float* outp = out + (long)m0 * 128;
    #pragma unroll
    for (int nt = 0; nt < 2; ++nt) {
        const int ob = wc * 32 + nt * 16 + lg * 4;     // 4 consecutive o per lane
        const float4 bias2 = *reinterpret_cast<const float4*>(b2 + ob);
        #pragma unroll
        for (int mt = 0; mt < 2; ++mt) {
            const int m = wr * 32 + mt * 16 + lr;
            float4 v;
            v.x = acc2[nt][mt][0] + bias2.x;
            v.y = acc2[nt][mt][1] + bias2.y;
            v.z = acc2[nt][mt][2] + bias2.z;
            v.w = acc2[nt][mt][3] + bias2.w;
            *reinterpret_cast<float4*>(outp + m * 128 + ob) = v;
        }
    }
}

extern "C" void kernel_launch(void* const* d_in, const int* in_sizes, int n_in,
                              void* d_out, int out_size, void* d_ws, size_t ws_size,
                              hipStream_t stream) {
    const float* span = (const float*)d_in[0];
    const int*   rel  = (const int*)d_in[1];
    const float* W1   = (const float*)d_in[2];
    const float* b1   = (const float*)d_in[3];
    const float* W2   = (const float*)d_in[4];
    const float* b2   = (const float*)d_in[5];
    float* out = (float*)d_out;

    unsigned short* spanbf = (unsigned short*)d_ws;        // 2 MiB
    unsigned short* W1T = spanbf + B_ * S_ * H_;           // 192 KiB
    unsigned short* W2T = W1T + D_ * F_;                   // 96 KiB

    k_prep<<<1600, 256, 0, stream>>>(span, W1, W2, spanbf, W1T, W2T);
    k_main<<<(B_ * R_) / 64, 512, 81920, stream>>>(spanbf, rel, W1T, b1, W2T, b2, out);
}